// Round 3
// baseline (80.300 us; speedup 1.0000x reference)
//
#include <hip/hip_runtime.h>
#include <math.h>

// Batched FK chain: re = T1..T25; out = concat(points = re[:3,3], vectors = re[:3,2]).
// Constant matrices are signed permutes + translations; propagate p (w=1) and
// v (w=0) right-to-left through the chain.
//
// R3: 4 items per thread, no LDS, no barriers. 4 items x 7 angles = 28 floats =
// exactly 7 float4 per thread (112 B, 16B-aligned per thread since 112%16==0).
// Outputs: 4 items x 3 floats = 3 float4 for points and 3 for vectors (48 B,
// 48%16==0). Every 64B line is fetched once from HBM; the 4-sector re-touches
// across the 7 load instrs hit L1. 7 independent outstanding loads/thread +
// 4 independent chains give the ILP that the old barrier-serialized LDS
// version lacked.

#define DEGf 0.017453292519943295f

__device__ __forceinline__ void rotz(float& x, float& y, float c, float s) {
    float nx = c * x - s * y;
    float ny = s * x + c * y;
    x = nx; y = ny;
}

__device__ __forceinline__ void fk_chain(const float* __restrict__ th,
                                         float* __restrict__ pr,
                                         float* __restrict__ vr) {
    // Angles in radians (signs/scales folded from the reference chain)
    const float a0 = th[0] * DEGf;
    const float a1 = th[1] * DEGf;
    const float a2 = -th[2] * DEGf;
    const float a3 = -th[3] * DEGf;
    const float a4 = th[4] * (-0.5f * DEGf);
    const float a5 = (th[5] * (1.0f / 4.5f) + 10.0f) * DEGf;
    const float a6 = (20.0f + (th[6] + 180.0f) * (1.0f / 4.5f)) * DEGf;

    float s0, c0, s1, c1, s2, c2, s3, c3, s4, c4, s5, c5, s6, c6;
    __sincosf(a0, &s0, &c0);
    __sincosf(a1, &s1, &c1);
    __sincosf(a2, &s2, &c2);
    __sincosf(a3, &s3, &c3);
    __sincosf(a4, &s4, &c4);
    __sincosf(a5, &s5, &c5);
    __sincosf(a6, &s6, &c6);

    // After T25=Ry(90): p = col3 = (0,0,0); v = col2 = (1,0,0).
    float px = 6.0f, py = 0.0f, pz = 0.0f;   // T24: Txyz(6,0,0)
    float vx = 1.0f, vy = 0.0f, vz = 0.0f;
    float t;

    rotz(px, py, c6, s6); rotz(vx, vy, c6, s6);      // T23 = Rz(a6)
    px += 6.0f; py -= 1.0f;                          // T22, T21
    rotz(px, py, c5, s5); rotz(vx, vy, c5, s5);      // T20 = Rz(a5)
    t = px; px = py; py = -t;                        // T19 = Rz(-90)
    t = vx; vx = vy; vy = -t;
    t = py; py = pz; pz = -t;                        // T18 = Rx(-90)
    t = vy; vy = vz; vz = -t;
    pz += 10.0f;                                     // T17
    rotz(px, py, c4, s4); rotz(vx, vy, c4, s4);      // T16 = Rz(a4)
    t = px; px = pz; pz = -t;                        // T15 = Ry(90)
    t = vx; vx = vz; vz = -t;
    px += 10.0f;                                     // T14
    rotz(px, py, c3, s3); rotz(vx, vy, c3, s3);      // T13 = Rz(a3)
    px = -px; py = -py; vx = -vx; vy = -vy;          // T12 = Rz(180)
    t = py; py = -pz; pz = t;                        // T11 = Rx(90)
    t = vy; vy = -vz; vz = t;
    px += 17.5f;                                     // T10
    rotz(px, py, c2, s2); rotz(vx, vy, c2, s2);      // T9 = Rz(a2)
    t = py; py = pz; pz = -t;                        // T8 = Rx(-90)
    t = vy; vy = vz; vz = -t;
    px += 3.0f; pz += 9.5f;                          // T7
    rotz(px, py, c1, s1); rotz(vx, vy, c1, s1);      // T6 = Rz(a1)
    t = px; px = pz; pz = -t;                        // T5 = Ry(90)
    t = vx; vx = vz; vz = -t;
    py -= 1.5f; pz += 2.5f;                          // T4
    rotz(px, py, c0, s0); rotz(vx, vy, c0, s0);      // T3 = Rz(a0)
    t = px; px = -py; py = t;                        // T2 = Rz(90)
    t = vx; vx = -vy; vy = t;
    py += 5.0f; pz += 19.5f;                         // T1

    pr[0] = px; pr[1] = py; pr[2] = pz;
    vr[0] = vx; vr[1] = vy; vr[2] = vz;
}

__global__ __launch_bounds__(256) void fk4_kernel(const float* __restrict__ thetas,
                                                  float* __restrict__ out,
                                                  int B) {
    const long long q = (long long)blockIdx.x * 256 + threadIdx.x;  // quad index
    const long long i0 = q * 4;

    if (i0 + 4 <= (long long)B) {
        // --- load: 7 float4 = 28 angles = items [i0, i0+4) ---
        float4 Abuf[7];
        const float4* t4 = (const float4*)(thetas + i0 * 7);
#pragma unroll
        for (int j = 0; j < 7; ++j) Abuf[j] = t4[j];
        const float* a = (const float*)Abuf;  // item k's angles: a[k*7 .. k*7+6]

        float4 Pbuf[3];
        float4 Vbuf[3];
        float* po = (float*)Pbuf;
        float* vo = (float*)Vbuf;

#pragma unroll
        for (int k = 0; k < 4; ++k)
            fk_chain(a + k * 7, po + k * 3, vo + k * 3);

        float4* o4p = (float4*)(out + i0 * 3);
        o4p[0] = Pbuf[0]; o4p[1] = Pbuf[1]; o4p[2] = Pbuf[2];
        float4* o4v = (float4*)(out + (long long)B * 3 + i0 * 3);
        o4v[0] = Vbuf[0]; o4v[1] = Vbuf[1]; o4v[2] = Vbuf[2];
    } else {
        // scalar tail (not taken for B = 1M)
        for (long long i = i0; i < (long long)B; ++i) {
            float th[7];
#pragma unroll
            for (int j = 0; j < 7; ++j) th[j] = thetas[i * 7 + j];
            float pr[3], vr[3];
            fk_chain(th, pr, vr);
            float* p = out + 3ll * i;
            p[0] = pr[0]; p[1] = pr[1]; p[2] = pr[2];
            float* v = out + 3ll * (long long)B + 3ll * i;
            v[0] = vr[0]; v[1] = vr[1]; v[2] = vr[2];
        }
    }
}

extern "C" void kernel_launch(void* const* d_in, const int* in_sizes, int n_in,
                              void* d_out, int out_size, void* d_ws, size_t ws_size,
                              hipStream_t stream) {
    const float* thetas = (const float*)d_in[0];
    float* out = (float*)d_out;
    const int B = in_sizes[0] / 7;
    const long long nq = ((long long)B + 3) / 4;
    const int block = 256;
    const int grid = (int)((nq + block - 1) / block);
    fk4_kernel<<<grid, block, 0, stream>>>(thetas, out, B);
}

// Round 4
// 76.863 us; speedup vs baseline: 1.0447x; 1.0447x over previous
//
#include <hip/hip_runtime.h>
#include <math.h>

// Batched FK chain: re = T1..T25; out = concat(points = re[:3,3], vectors = re[:3,2]).
// Constant matrices are signed permutes + translations; propagate p (w=1) and
// v (w=0) right-to-left. Fully float4-vectorized I/O via LDS staging:
//   in:  7 floats/item -> 448 float4 per 256-item block (coalesced)
//   out: 2x3 floats/item -> 2x192 float4 per block (coalesced)
// R4: disjoint input/output LDS regions -> only 2 barriers (R2 had 3).
// LDS strides 7 and 3 are odd -> <=2-way bank aliasing = free (G4/m136).

#define DEGf 0.017453292519943295f

__device__ __forceinline__ void rotz(float& x, float& y, float c, float s) {
    float nx = c * x - s * y;
    float ny = s * x + c * y;
    x = nx; y = ny;
}

__global__ __launch_bounds__(256) void fk_kernel(const float* __restrict__ thetas,
                                                 float* __restrict__ out,
                                                 int B) {
    __shared__ float sin_buf[7 * 256];   // input stage: 1792 floats
    __shared__ float sout_buf[6 * 256];  // output stage: 1536 floats
    float4* si4 = (float4*)sin_buf;
    float4* so4 = (float4*)sout_buf;
    const int tid = threadIdx.x;
    const long long blockBase = (long long)blockIdx.x * 256;
    const bool full = (blockBase + 256 <= (long long)B) && ((B & 3) == 0);

    float th[7];
    if (full) {
        // 448 float4 = 1792 floats staged per block, fully coalesced
        const float4* t4 = (const float4*)(thetas + blockBase * 7);
        si4[tid] = t4[tid];
        if (tid < 192) si4[256 + tid] = t4[256 + tid];
        __syncthreads();
#pragma unroll
        for (int j = 0; j < 7; ++j) th[j] = sin_buf[tid * 7 + j];
    } else {
        const long long i = blockBase + tid;
        if (i >= B) return;
#pragma unroll
        for (int j = 0; j < 7; ++j) th[j] = thetas[i * 7 + j];
    }

    // Angles in radians (signs/scales folded from the reference chain)
    const float a0 = th[0] * DEGf;
    const float a1 = th[1] * DEGf;
    const float a2 = -th[2] * DEGf;
    const float a3 = -th[3] * DEGf;
    const float a4 = th[4] * (-0.5f * DEGf);
    const float a5 = (th[5] * (1.0f / 4.5f) + 10.0f) * DEGf;
    const float a6 = (20.0f + (th[6] + 180.0f) * (1.0f / 4.5f)) * DEGf;

    float s0, c0, s1, c1, s2, c2, s3, c3, s4v, c4, s5, c5, s6, c6;
    __sincosf(a0, &s0, &c0);
    __sincosf(a1, &s1, &c1);
    __sincosf(a2, &s2, &c2);
    __sincosf(a3, &s3, &c3);
    __sincosf(a4, &s4v, &c4);
    __sincosf(a5, &s5, &c5);
    __sincosf(a6, &s6, &c6);

    // After T25=Ry(90): p = col3 = (0,0,0); v = col2 = (1,0,0).
    float px = 6.0f, py = 0.0f, pz = 0.0f;   // T24: Txyz(6,0,0)
    float vx = 1.0f, vy = 0.0f, vz = 0.0f;
    float t;

    rotz(px, py, c6, s6); rotz(vx, vy, c6, s6);      // T23 = Rz(a6)
    px += 6.0f; py -= 1.0f;                          // T22, T21
    rotz(px, py, c5, s5); rotz(vx, vy, c5, s5);      // T20 = Rz(a5)
    t = px; px = py; py = -t;                        // T19 = Rz(-90)
    t = vx; vx = vy; vy = -t;
    t = py; py = pz; pz = -t;                        // T18 = Rx(-90)
    t = vy; vy = vz; vz = -t;
    pz += 10.0f;                                     // T17
    rotz(px, py, c4, s4v); rotz(vx, vy, c4, s4v);    // T16 = Rz(a4)
    t = px; px = pz; pz = -t;                        // T15 = Ry(90)
    t = vx; vx = vz; vz = -t;
    px += 10.0f;                                     // T14
    rotz(px, py, c3, s3); rotz(vx, vy, c3, s3);      // T13 = Rz(a3)
    px = -px; py = -py; vx = -vx; vy = -vy;          // T12 = Rz(180)
    t = py; py = -pz; pz = t;                        // T11 = Rx(90)
    t = vy; vy = -vz; vz = t;
    px += 17.5f;                                     // T10
    rotz(px, py, c2, s2); rotz(vx, vy, c2, s2);      // T9 = Rz(a2)
    t = py; py = pz; pz = -t;                        // T8 = Rx(-90)
    t = vy; vy = vz; vz = -t;
    px += 3.0f; pz += 9.5f;                          // T7
    rotz(px, py, c1, s1); rotz(vx, vy, c1, s1);      // T6 = Rz(a1)
    t = px; px = pz; pz = -t;                        // T5 = Ry(90)
    t = vx; vx = vz; vz = -t;
    py -= 1.5f; pz += 2.5f;                          // T4
    rotz(px, py, c0, s0); rotz(vx, vy, c0, s0);      // T3 = Rz(a0)
    t = px; px = -py; py = t;                        // T2 = Rz(90)
    t = vx; vx = -vy; vy = t;
    py += 5.0f; pz += 19.5f;                         // T1

    if (full) {
        // stage: points in sout_buf[0..768), vectors in sout_buf[768..1536)
        sout_buf[tid * 3 + 0] = px;
        sout_buf[tid * 3 + 1] = py;
        sout_buf[tid * 3 + 2] = pz;
        sout_buf[768 + tid * 3 + 0] = vx;
        sout_buf[768 + tid * 3 + 1] = vy;
        sout_buf[768 + tid * 3 + 2] = vz;
        __syncthreads();
        float4* o4p = (float4*)(out + blockBase * 3);
        float4* o4v = (float4*)(out + (long long)B * 3 + blockBase * 3);
        if (tid < 192) {
            o4p[tid] = so4[tid];
            o4v[tid] = so4[192 + tid];
        }
    } else {
        const long long i = blockBase + tid;
        float* po = out + 3ll * i;
        po[0] = px; po[1] = py; po[2] = pz;
        float* vo = out + 3ll * (long long)B + 3ll * i;
        vo[0] = vx; vo[1] = vy; vo[2] = vz;
    }
}

extern "C" void kernel_launch(void* const* d_in, const int* in_sizes, int n_in,
                              void* d_out, int out_size, void* d_ws, size_t ws_size,
                              hipStream_t stream) {
    const float* thetas = (const float*)d_in[0];
    float* out = (float*)d_out;
    const int B = in_sizes[0] / 7;
    const int block = 256;
    const int grid = (B + block - 1) / block;
    fk_kernel<<<grid, block, 0, stream>>>(thetas, out, B);
}